// Round 7
// baseline (201.531 us; speedup 1.0000x reference)
//
#include <hip/hip_runtime.h>
#include <hip/hip_cooperative_groups.h>

namespace cg = cooperative_groups;

#define BATCH       65536
#define FEAT        256
#define NUM_CLASSES 10000
#define ALPHA       0.5f
#define CAP         32     // bucket capacity; Poisson(6.55) max over 10k classes ~21

#define BLOCKS      1024
#define THREADS     256
#define GRID_T      (BLOCKS * THREADS)          // 262144
#define NWAVES      (GRID_T / 64)               // 4096 waves

// ---------------------------------------------------------------------------
// Single cooperative kernel:
//   P1: zero per-class counters (+ overflow counter)
//   P2: bucket scatter  pos = atomicAdd(count[c]); bucket[c*CAP+pos] = i
//   P3: one wave per class (grid-strided): gather y_pred rows, per-sample
//       loss, new_centers = c - ALPHA*(n*c - sum_y)/(n+1)
// Replaces 3 kernels + 2 launch gaps with 2 grid.sync().
// ---------------------------------------------------------------------------
__global__ __launch_bounds__(THREADS, 4) void fused_kernel(
    const float* __restrict__ y_pred,
    const float* __restrict__ centers,
    const int*   __restrict__ y_true,
    int*         __restrict__ count,      // [NUM_CLASSES + 1] (last = ovf count)
    int*         __restrict__ bucket,     // [NUM_CLASSES * CAP]
    int*         __restrict__ ovf,        // [2 * BATCH]
    float*       __restrict__ loss,       // [BATCH]
    float*       __restrict__ new_centers)// [NUM_CLASSES * FEAT]
{
    cg::grid_group grid = cg::this_grid();

    const int t    = threadIdx.x;
    const int gtid = blockIdx.x * THREADS + t;

    // ---- P1: zero counters -------------------------------------------------
    if (gtid < NUM_CLASSES + 1) count[gtid] = 0;
    grid.sync();

    // ---- P2: bucket scatter (spread: 16 int4 per block) --------------------
    {
        const int w = blockIdx.x * 16 + t;          // 1024*16 = 16384 int4s
        if (t < 16) {
            const int4 c4 = reinterpret_cast<const int4*>(y_true)[w];
            const int s0  = w * 4;
            int* ovfcnt = count + NUM_CLASSES;
            const int cs[4] = {c4.x, c4.y, c4.z, c4.w};
            #pragma unroll
            for (int j = 0; j < 4; ++j) {
                const int c   = cs[j];
                const int pos = atomicAdd(&count[c], 1);
                if (pos < CAP) {
                    bucket[c * CAP + pos] = s0 + j;
                } else {
                    const int o = atomicAdd(ovfcnt, 1);
                    ovf[2 * o]     = c;
                    ovf[2 * o + 1] = s0 + j;
                }
            }
        }
    }
    grid.sync();

    // ---- P3: per-class gather / loss / center update -----------------------
    const int lane = t & 63;
    const int wid  = gtid >> 6;                     // global wave id

    for (int c = wid; c < NUM_CLASSES; c += NWAVES) {
        const int n_total = count[c];
        const int n       = min(n_total, CAP);

        float4 cv = reinterpret_cast<const float4*>(centers + (size_t)c * FEAT)[lane];
        float4 s  = make_float4(0.f, 0.f, 0.f, 0.f);

        const int bidx = (lane < n) ? bucket[c * CAP + lane] : 0;

        for (int k = 0; k < n; ++k) {
            const int idx = __shfl(bidx, k, 64);
            float4 y = reinterpret_cast<const float4*>(y_pred + (size_t)idx * FEAT)[lane];
            s.x += y.x; s.y += y.y; s.z += y.z; s.w += y.w;

            float dx = cv.x - y.x, dy = cv.y - y.y,
                  dz = cv.z - y.z, dw = cv.w - y.w;
            float l = dx*dx + dy*dy + dz*dz + dw*dw;
            #pragma unroll
            for (int off = 32; off > 0; off >>= 1)
                l += __shfl_down(l, off, 64);
            if (lane == 0) loss[idx] = l;
        }

        // overflow fallback (statistically never taken; kept for correctness)
        if (n_total > CAP) {
            const int m = count[NUM_CLASSES];
            for (int o = 0; o < m; ++o) {
                if (ovf[2 * o] == c) {
                    const int idx = ovf[2 * o + 1];
                    float4 y = reinterpret_cast<const float4*>(y_pred + (size_t)idx * FEAT)[lane];
                    s.x += y.x; s.y += y.y; s.z += y.z; s.w += y.w;
                    float dx = cv.x - y.x, dy = cv.y - y.y,
                          dz = cv.z - y.z, dw = cv.w - y.w;
                    float l = dx*dx + dy*dy + dz*dz + dw*dw;
                    #pragma unroll
                    for (int off = 32; off > 0; off >>= 1)
                        l += __shfl_down(l, off, 64);
                    if (lane == 0) loss[idx] = l;
                }
            }
        }

        const float fn    = (float)n_total;
        const float scale = ALPHA / (fn + 1.0f);
        float4 o;
        o.x = cv.x - (fn * cv.x - s.x) * scale;
        o.y = cv.y - (fn * cv.y - s.y) * scale;
        o.z = cv.z - (fn * cv.z - s.z) * scale;
        o.w = cv.w - (fn * cv.w - s.w) * scale;
        reinterpret_cast<float4*>(new_centers + (size_t)c * FEAT)[lane] = o;
    }
}

extern "C" void kernel_launch(void* const* d_in, const int* in_sizes, int n_in,
                              void* d_out, int out_size, void* d_ws, size_t ws_size,
                              hipStream_t stream)
{
    const float* y_pred  = (const float*)d_in[0];
    const float* centers = (const float*)d_in[1];
    const int*   y_true  = (const int*)d_in[2];

    float* out         = (float*)d_out;
    float* loss        = out;                 // [BATCH]
    float* new_centers = out + BATCH;         // [NUM_CLASSES * FEAT]

    int* count  = (int*)d_ws;                         // [NUM_CLASSES + 1]
    int* bucket = count + NUM_CLASSES + 1;            // [NUM_CLASSES * CAP]
    int* ovf    = bucket + NUM_CLASSES * CAP;         // [2 * BATCH]

    void* args[] = {
        (void*)&y_pred, (void*)&centers, (void*)&y_true,
        (void*)&count, (void*)&bucket, (void*)&ovf,
        (void*)&loss, (void*)&new_centers
    };

    hipLaunchCooperativeKernel((const void*)fused_kernel,
                               dim3(BLOCKS), dim3(THREADS),
                               args, 0, stream);
}

// Round 8
// 32.418 us; speedup vs baseline: 6.2166x; 6.2166x over previous
//
#include <hip/hip_runtime.h>

#define BATCH       65536
#define FEAT        256
#define NUM_CLASSES 10000
#define ALPHA       0.5f
#define CAP         32     // bucket capacity; Poisson(6.55) max over 10k classes ~21

// ---------------------------------------------------------------------------
// K1: zero per-class counters + overflow counter
// ---------------------------------------------------------------------------
__global__ __launch_bounds__(256) void zero_kernel(int* __restrict__ count)
{
    int i = blockIdx.x * 256 + threadIdx.x;
    if (i < NUM_CLASSES + 1) count[i] = 0;
}

// ---------------------------------------------------------------------------
// K2: bucket scatter, one sample per thread (shortest possible atomic chain).
// pos = atomicAdd(count[c]); bucket[c*CAP+pos] = i. Overflow list for the
// (statistically impossible, but handled) case pos >= CAP.
// ---------------------------------------------------------------------------
__global__ __launch_bounds__(256) void bucket_kernel(const int* __restrict__ y_true,
                                                     int* __restrict__ count,
                                                     int* __restrict__ bucket,
                                                     int* __restrict__ ovf)
{
    const int i = blockIdx.x * 256 + threadIdx.x;   // 0 .. BATCH-1
    const int c = y_true[i];
    const int pos = atomicAdd(&count[c], 1);
    if (pos < CAP) {
        bucket[c * CAP + pos] = i;
    } else {
        const int o = atomicAdd(count + NUM_CLASSES, 1);
        ovf[2 * o]     = c;
        ovf[2 * o + 1] = i;
    }
}

// ---------------------------------------------------------------------------
// K3: one wave per class, gather unrolled x4. Four independent 1KB row loads
// in flight per iteration; four loss-reduce shfl chains interleaved to hide
// ds_bpermute latency. Validity (kk < n) is wave-uniform.
// ---------------------------------------------------------------------------
__global__ __launch_bounds__(256) void class_kernel(
    const float* __restrict__ y_pred,
    const float* __restrict__ centers,
    const int*   __restrict__ count,
    const int*   __restrict__ bucket,
    const int*   __restrict__ ovf,
    float*       __restrict__ loss,
    float*       __restrict__ new_centers)
{
    const int wave = threadIdx.x >> 6;
    const int lane = threadIdx.x & 63;
    const int c    = blockIdx.x * 4 + wave;      // exact: 2500*4 = 10000
    if (c >= NUM_CLASSES) return;

    const int n_total = count[c];
    const int n       = min(n_total, CAP);

    float4 cv = reinterpret_cast<const float4*>(centers + (size_t)c * FEAT)[lane];
    float4 s  = make_float4(0.f, 0.f, 0.f, 0.f);

    const int bidx = (lane < n) ? bucket[c * CAP + lane] : 0;

    for (int k0 = 0; k0 < n; k0 += 4) {
        const bool v1 = (k0 + 1) < n;
        const bool v2 = (k0 + 2) < n;
        const bool v3 = (k0 + 3) < n;

        const int i0 = __shfl(bidx, k0, 64);
        const int i1 = __shfl(bidx, v1 ? k0 + 1 : k0, 64);
        const int i2 = __shfl(bidx, v2 ? k0 + 2 : k0, 64);
        const int i3 = __shfl(bidx, v3 ? k0 + 3 : k0, 64);

        // 4 independent 1KB row loads in flight
        const float4 y0 = reinterpret_cast<const float4*>(y_pred + (size_t)i0 * FEAT)[lane];
        const float4 y1 = reinterpret_cast<const float4*>(y_pred + (size_t)i1 * FEAT)[lane];
        const float4 y2 = reinterpret_cast<const float4*>(y_pred + (size_t)i2 * FEAT)[lane];
        const float4 y3 = reinterpret_cast<const float4*>(y_pred + (size_t)i3 * FEAT)[lane];

        const float w1 = v1 ? 1.f : 0.f;
        const float w2 = v2 ? 1.f : 0.f;
        const float w3 = v3 ? 1.f : 0.f;

        s.x += y0.x + w1 * y1.x + w2 * y2.x + w3 * y3.x;
        s.y += y0.y + w1 * y1.y + w2 * y2.y + w3 * y3.y;
        s.z += y0.z + w1 * y1.z + w2 * y2.z + w3 * y3.z;
        s.w += y0.w + w1 * y1.w + w2 * y2.w + w3 * y3.w;

        float dx, dy, dz, dw;
        dx = cv.x - y0.x; dy = cv.y - y0.y; dz = cv.z - y0.z; dw = cv.w - y0.w;
        float l0 = dx*dx + dy*dy + dz*dz + dw*dw;
        dx = cv.x - y1.x; dy = cv.y - y1.y; dz = cv.z - y1.z; dw = cv.w - y1.w;
        float l1 = dx*dx + dy*dy + dz*dz + dw*dw;
        dx = cv.x - y2.x; dy = cv.y - y2.y; dz = cv.z - y2.z; dw = cv.w - y2.w;
        float l2 = dx*dx + dy*dy + dz*dz + dw*dw;
        dx = cv.x - y3.x; dy = cv.y - y3.y; dz = cv.z - y3.z; dw = cv.w - y3.w;
        float l3 = dx*dx + dy*dy + dz*dz + dw*dw;

        // 4 interleaved butterfly reduces (independent bpermute chains)
        #pragma unroll
        for (int off = 32; off > 0; off >>= 1) {
            l0 += __shfl_down(l0, off, 64);
            l1 += __shfl_down(l1, off, 64);
            l2 += __shfl_down(l2, off, 64);
            l3 += __shfl_down(l3, off, 64);
        }

        if (lane == 0) {
            loss[i0] = l0;
            if (v1) loss[i1] = l1;
            if (v2) loss[i2] = l2;
            if (v3) loss[i3] = l3;
        }
    }

    // overflow fallback (never taken for this data; kept for correctness)
    if (n_total > CAP) {
        const int m = count[NUM_CLASSES];
        for (int o = 0; o < m; ++o) {
            if (ovf[2 * o] == c) {
                const int idx = ovf[2 * o + 1];
                float4 y = reinterpret_cast<const float4*>(y_pred + (size_t)idx * FEAT)[lane];
                s.x += y.x; s.y += y.y; s.z += y.z; s.w += y.w;
                float dx = cv.x - y.x, dy = cv.y - y.y,
                      dz = cv.z - y.z, dw = cv.w - y.w;
                float l = dx*dx + dy*dy + dz*dz + dw*dw;
                #pragma unroll
                for (int off = 32; off > 0; off >>= 1)
                    l += __shfl_down(l, off, 64);
                if (lane == 0) loss[idx] = l;
            }
        }
    }

    const float fn    = (float)n_total;
    const float scale = ALPHA / (fn + 1.0f);
    float4 o;
    o.x = cv.x - (fn * cv.x - s.x) * scale;
    o.y = cv.y - (fn * cv.y - s.y) * scale;
    o.z = cv.z - (fn * cv.z - s.z) * scale;
    o.w = cv.w - (fn * cv.w - s.w) * scale;
    reinterpret_cast<float4*>(new_centers + (size_t)c * FEAT)[lane] = o;
}

extern "C" void kernel_launch(void* const* d_in, const int* in_sizes, int n_in,
                              void* d_out, int out_size, void* d_ws, size_t ws_size,
                              hipStream_t stream)
{
    const float* y_pred  = (const float*)d_in[0];
    const float* centers = (const float*)d_in[1];
    const int*   y_true  = (const int*)d_in[2];

    float* out         = (float*)d_out;
    float* loss        = out;                 // [BATCH]
    float* new_centers = out + BATCH;         // [NUM_CLASSES * FEAT]

    int* count  = (int*)d_ws;                         // [NUM_CLASSES + 1]
    int* bucket = count + NUM_CLASSES + 1;            // [NUM_CLASSES * CAP]
    int* ovf    = bucket + NUM_CLASSES * CAP;         // [2 * BATCH]

    zero_kernel  <<<(NUM_CLASSES + 256) / 256, 256, 0, stream>>>(count);
    bucket_kernel<<<BATCH / 256, 256, 0, stream>>>(y_true, count, bucket, ovf);
    class_kernel <<<NUM_CLASSES / 4, 256, 0, stream>>>(
        y_pred, centers, count, bucket, ovf, loss, new_centers);
}

// Round 9
// 32.414 us; speedup vs baseline: 6.2174x; 1.0001x over previous
//
#include <hip/hip_runtime.h>

#define BATCH       65536
#define FEAT        256
#define NUM_CLASSES 10000
#define ALPHA       0.5f
#define CAP         32     // bucket capacity; Poisson(6.55) max over 10k classes ~21
#define UNROLL      8

// ---------------------------------------------------------------------------
// K1: zero per-class counters + overflow counter
// ---------------------------------------------------------------------------
__global__ __launch_bounds__(256) void zero_kernel(int* __restrict__ count)
{
    int i = blockIdx.x * 256 + threadIdx.x;
    if (i < NUM_CLASSES + 1) count[i] = 0;
}

// ---------------------------------------------------------------------------
// K2: bucket scatter, one sample per thread.
// pos = atomicAdd(count[c]); bucket[c*CAP+pos] = i. Overflow list handles the
// (statistically impossible) pos >= CAP case.
// ---------------------------------------------------------------------------
__global__ __launch_bounds__(256) void bucket_kernel(const int* __restrict__ y_true,
                                                     int* __restrict__ count,
                                                     int* __restrict__ bucket,
                                                     int* __restrict__ ovf)
{
    const int i = blockIdx.x * 256 + threadIdx.x;   // 0 .. BATCH-1
    const int c = y_true[i];
    const int pos = atomicAdd(&count[c], 1);
    if (pos < CAP) {
        bucket[c * CAP + pos] = i;
    } else {
        const int o = atomicAdd(count + NUM_CLASSES, 1);
        ovf[2 * o]     = c;
        ovf[2 * o + 1] = i;
    }
}

// ---------------------------------------------------------------------------
// K3: ONE WAVE PER CLASS (64-thread blocks -> wave-granular load balancing
// across the Poisson class-size distribution). Gather unrolled x8: 8
// independent 1KB row loads in flight; 8 interleaved loss butterflies.
// Index broadcast via readlane (wave-uniform k -> SGPR base address).
// ---------------------------------------------------------------------------
__global__ __launch_bounds__(64) void class_kernel(
    const float* __restrict__ y_pred,
    const float* __restrict__ centers,
    const int*   __restrict__ count,
    const int*   __restrict__ bucket,
    const int*   __restrict__ ovf,
    float*       __restrict__ loss,
    float*       __restrict__ new_centers)
{
    const int lane = threadIdx.x;        // 0..63
    const int c    = blockIdx.x;         // one class per block/wave
    if (c >= NUM_CLASSES) return;

    const int n_total = count[c];
    const int n       = min(n_total, CAP);

    float4 cv = reinterpret_cast<const float4*>(centers + (size_t)c * FEAT)[lane];
    float4 s  = make_float4(0.f, 0.f, 0.f, 0.f);

    const int bidx = (lane < n) ? bucket[c * CAP + lane] : 0;

    for (int k0 = 0; k0 < n; k0 += UNROLL) {
        int    idx[UNROLL];
        bool   vj [UNROLL];
        float4 y  [UNROLL];
        float  l  [UNROLL];

        #pragma unroll
        for (int j = 0; j < UNROLL; ++j) {
            const int  kk = k0 + j;
            vj[j]  = (kk < n);
            idx[j] = __builtin_amdgcn_readlane(bidx, vj[j] ? kk : k0);
        }
        #pragma unroll
        for (int j = 0; j < UNROLL; ++j)
            y[j] = reinterpret_cast<const float4*>(y_pred + (size_t)idx[j] * FEAT)[lane];

        #pragma unroll
        for (int j = 0; j < UNROLL; ++j) {
            const float w = vj[j] ? 1.f : 0.f;
            s.x += w * y[j].x;
            s.y += w * y[j].y;
            s.z += w * y[j].z;
            s.w += w * y[j].w;
            const float dx = cv.x - y[j].x, dy = cv.y - y[j].y,
                        dz = cv.z - y[j].z, dw = cv.w - y[j].w;
            l[j] = dx*dx + dy*dy + dz*dz + dw*dw;
        }

        // 8 interleaved butterfly reduces (independent cross-lane chains)
        #pragma unroll
        for (int off = 32; off > 0; off >>= 1) {
            #pragma unroll
            for (int j = 0; j < UNROLL; ++j)
                l[j] += __shfl_down(l[j], off, 64);
        }

        if (lane == 0) {
            #pragma unroll
            for (int j = 0; j < UNROLL; ++j)
                if (vj[j]) loss[idx[j]] = l[j];
        }
    }

    // overflow fallback (never taken for this data; kept for correctness)
    if (n_total > CAP) {
        const int m = count[NUM_CLASSES];
        for (int o = 0; o < m; ++o) {
            if (ovf[2 * o] == c) {
                const int idx = ovf[2 * o + 1];
                float4 y = reinterpret_cast<const float4*>(y_pred + (size_t)idx * FEAT)[lane];
                s.x += y.x; s.y += y.y; s.z += y.z; s.w += y.w;
                float dx = cv.x - y.x, dy = cv.y - y.y,
                      dz = cv.z - y.z, dw = cv.w - y.w;
                float l = dx*dx + dy*dy + dz*dz + dw*dw;
                #pragma unroll
                for (int off = 32; off > 0; off >>= 1)
                    l += __shfl_down(l, off, 64);
                if (lane == 0) loss[idx] = l;
            }
        }
    }

    const float fn    = (float)n_total;
    const float scale = ALPHA / (fn + 1.0f);
    float4 o;
    o.x = cv.x - (fn * cv.x - s.x) * scale;
    o.y = cv.y - (fn * cv.y - s.y) * scale;
    o.z = cv.z - (fn * cv.z - s.z) * scale;
    o.w = cv.w - (fn * cv.w - s.w) * scale;
    reinterpret_cast<float4*>(new_centers + (size_t)c * FEAT)[lane] = o;
}

extern "C" void kernel_launch(void* const* d_in, const int* in_sizes, int n_in,
                              void* d_out, int out_size, void* d_ws, size_t ws_size,
                              hipStream_t stream)
{
    const float* y_pred  = (const float*)d_in[0];
    const float* centers = (const float*)d_in[1];
    const int*   y_true  = (const int*)d_in[2];

    float* out         = (float*)d_out;
    float* loss        = out;                 // [BATCH]
    float* new_centers = out + BATCH;         // [NUM_CLASSES * FEAT]

    int* count  = (int*)d_ws;                         // [NUM_CLASSES + 1]
    int* bucket = count + NUM_CLASSES + 1;            // [NUM_CLASSES * CAP]
    int* ovf    = bucket + NUM_CLASSES * CAP;         // [2 * BATCH]

    zero_kernel  <<<(NUM_CLASSES + 256) / 256, 256, 0, stream>>>(count);
    bucket_kernel<<<BATCH / 256, 256, 0, stream>>>(y_true, count, bucket, ovf);
    class_kernel <<<NUM_CLASSES, 64, 0, stream>>>(
        y_pred, centers, count, bucket, ovf, loss, new_centers);
}